// Round 10
// baseline (2423.158 us; speedup 1.0000x reference)
//
#include <hip/hip_runtime.h>

constexpr int NN = 50000;
constexpr int NE = 800000;
constexpr int XD = 92;
constexpr int ED = 80;
constexpr int HD = 128;
constexpr int C2 = 256;   // 2*HD
constexpr int IND = 336;  // 2*HD + ED
constexpr int NC = 3;
constexpr int NG = 256;
constexpr int NTILES = NE / 64;      // 12500
constexpr int WSZ_L = 16 * 3 * 64 * 8;   // per-layer swizzled W2 frags (ushort)
constexpr int WNP_L = 16 * 4 * 64 * 8;   // per-(layer,half) nodeproj W frags

#define DINL __device__ __forceinline__

typedef __attribute__((ext_vector_type(8))) short bf16x8;
typedef __attribute__((ext_vector_type(4))) float f32x4;

DINL short f2bf(float f) {
  unsigned u = __float_as_uint(f);
  u = (u + 0x7fffu + ((u >> 16) & 1u)) >> 16;
  return (short)u;
}
DINL float bf2f(unsigned short u) { return __uint_as_float(((unsigned)u) << 16); }
DINL float bflo(unsigned u) { return __uint_as_float(u << 16); }
DINL float bfhi(unsigned u) { return __uint_as_float(u & 0xffff0000u); }
DINL float rcp_(float x) {
  float r;
  asm("v_rcp_f32 %0, %1" : "=v"(r) : "v"(x));
  return r;
}
DINL float softplusf_(float x) { return x > 20.f ? x : log1pf(__expf(x)); }
DINL float gate_(float f, float cr) {
  float e = __expf(-f);
  float s = rcp_(1.f + e);
  float t = __expf(cr);
  float l = (cr > 15.f) ? cr : __logf(1.f + t);
  return s * l;
}

template <int CTRL>
DINL int dpp_i(int old_, int src) {
  return __builtin_amdgcn_update_dpp(old_, src, CTRL, 0xF, 0xF, false);
}
template <int CTRL>
DINL float dpp_f(float old_, float src) {
  return __int_as_float(
      __builtin_amdgcn_update_dpp(__float_as_int(old_), __float_as_int(src), CTRL, 0xF, 0xF, false));
}
constexpr int SHR1 = 0x111, SHR2 = 0x112, SHR4 = 0x114, SHR8 = 0x118, SHL1 = 0x101;

// ---------------- embed ----------------
__global__ __launch_bounds__(256) void k_embed(const float* __restrict__ x,
    const float* __restrict__ W, const float* __restrict__ b, float* __restrict__ h,
    unsigned short* __restrict__ hbf) {
  __shared__ float xs[2][XD];
  int t = threadIdx.x;
  int n0 = blockIdx.x * 2;
  for (int i = t; i < 2 * XD; i += 256) xs[i / XD][i % XD] = x[(size_t)n0 * XD + i];
  __syncthreads();
  int lo = t >> 7, c = t & 127;
  float acc = b[c];
  for (int k = 0; k < XD; ++k) acc = fmaf(xs[lo][k], W[k * HD + c], acc);
  h[(size_t)(n0 + lo) * HD + c] = acc;
  hbf[(size_t)(n0 + lo) * HD + c] = (unsigned short)f2bf(acc);
}

// ---------------- CSR build ----------------
__global__ __launch_bounds__(256) void k_hist(const int* __restrict__ src,
                                              int* __restrict__ deg) {
  for (int e = blockIdx.x * 256 + threadIdx.x; e < NE; e += gridDim.x * 256)
    atomicAdd(&deg[src[e]], 1);
}

__global__ __launch_bounds__(1024) void k_scan(const int* __restrict__ deg,
                                               int* __restrict__ cursor) {
  __shared__ int sums[1024];
  int t = threadIdx.x;
  const int CH = 49;
  int b0 = t * CH;
  int s = 0;
  for (int i = 0; i < CH; ++i) {
    int idx = b0 + i;
    if (idx < NN) s += deg[idx];
  }
  sums[t] = s;
  __syncthreads();
  for (int off = 1; off < 1024; off <<= 1) {
    int v = (t >= off) ? sums[t - off] : 0;
    __syncthreads();
    sums[t] += v;
    __syncthreads();
  }
  int excl = (t == 0) ? 0 : sums[t - 1];
  for (int i = 0; i < CH; ++i) {
    int idx = b0 + i;
    if (idx < NN) {
      cursor[idx] = excl;
      excl += deg[idx];
    }
  }
}

__global__ __launch_bounds__(256) void k_scatter(const int* __restrict__ src,
    const int* __restrict__ dst, int* __restrict__ cursor, int* __restrict__ eid,
    int* __restrict__ ssort, int* __restrict__ dsort) {
  for (int e = blockIdx.x * 256 + threadIdx.x; e < NE; e += gridDim.x * 256) {
    int s = src[e];
    int pos = atomicAdd(&cursor[s], 1);
    eid[pos] = e;
    ssort[pos] = s;
    dsort[pos] = dst[e];
  }
}

// ---------------- W2 -> edge-GEMM MFMA fragments ----------------
__global__ __launch_bounds__(256) void k_wprep(const float* __restrict__ convW,
                                               unsigned short* __restrict__ Wswz) {
  int idx = blockIdx.x * 256 + threadIdx.x;
  if (idx >= NC * WSZ_L) return;
  int L = idx / WSZ_L;
  int rem = idx - L * WSZ_L;
  int mt = rem / 1536;
  int rem2 = rem - mt * 1536;
  int ks = rem2 >> 9;
  int lane = (rem2 >> 3) & 63;
  int j = rem2 & 7;
  int k = ks * 32 + (lane >> 4) * 8 + j;
  int m = mt * 16 + (lane & 15);
  float v = (k < ED) ? convW[(size_t)L * IND * C2 + (size_t)(HD + k) * C2 + m] : 0.f;
  Wswz[idx] = (unsigned short)f2bf(v);
}

// ---------------- W1/W3 -> nodeproj MFMA fragments ----------------
__global__ __launch_bounds__(256) void k_wprep2(const float* __restrict__ convW,
                                                unsigned short* __restrict__ Wn) {
  int idx = blockIdx.x * 256 + threadIdx.x;
  if (idx >= NC * 2 * WNP_L) return;
  int Lh = idx >> 15;
  int L = Lh >> 1, half = Lh & 1;
  int rem = idx & 32767;
  int mt = rem >> 11;
  int rem2 = rem & 2047;
  int ks = rem2 >> 9;
  int lane = (rem2 >> 3) & 63;
  int j = rem2 & 7;
  int k = ks * 32 + (lane >> 4) * 8 + j;
  int m = mt * 16 + (lane & 15);
  int row = (half ? 208 : 0) + k;
  Wn[idx] = (unsigned short)f2bf(convW[(size_t)L * IND * C2 + (size_t)row * C2 + m]);
}

// ---------------- nodeproj via MFMA; output in PERMUTED slot layout ----------------
__global__ __launch_bounds__(256) void k_nodeproj2(const unsigned short* __restrict__ hbf,
    const unsigned short* __restrict__ Wn, int L,
    ushort4* __restrict__ P1, ushort4* __restrict__ P3) {
  __shared__ bf16x8 hls[1024];
  __shared__ ushort4 outls[4096];
  int t = threadIdx.x, w = t >> 6, l = t & 63, g = l >> 4, c = l & 15;
  int n0 = blockIdx.x * 64;
  int half = blockIdx.y;
  for (int i = t; i < 1024; i += 256) {
    int node = i >> 4, chunk = i & 15;
    int gn = n0 + node;
    if (gn >= NN) gn = NN - 1;
    bf16x8 v = *(const bf16x8*)(hbf + (size_t)gn * HD + chunk * 8);
    hls[node * 16 + (chunk ^ (node & 7))] = v;
  }
  __syncthreads();
  const bf16x8* Wf = (const bf16x8*)(Wn + ((size_t)(L * 2 + half)) * WNP_L);
  bf16x8 af[4][4];
#pragma unroll
  for (int mm = 0; mm < 4; ++mm)
#pragma unroll
    for (int ks = 0; ks < 4; ++ks) af[mm][ks] = Wf[((w * 4 + mm) * 4 + ks) * 64 + l];
  f32x4 acc[4][4];
#pragma unroll
  for (int mm = 0; mm < 4; ++mm)
#pragma unroll
    for (int nt = 0; nt < 4; ++nt)
#pragma unroll
      for (int i = 0; i < 4; ++i) acc[mm][nt][i] = 0.f;
#pragma unroll
  for (int nt = 0; nt < 4; ++nt) {
    int node = nt * 16 + c;
#pragma unroll
    for (int ks = 0; ks < 4; ++ks) {
      bf16x8 b = hls[node * 16 + ((4 * ks + g) ^ (node & 7))];
#pragma unroll
      for (int mm = 0; mm < 4; ++mm)
        acc[mm][nt] = __builtin_amdgcn_mfma_f32_16x16x32_bf16(af[mm][ks], b, acc[mm][nt], 0, 0, 0);
    }
  }
  __syncthreads();
#pragma unroll
  for (int mm = 0; mm < 4; ++mm) {
    int mt = w * 4 + mm;
    int wE = (mt & 7) >> 1;
    int mE = (mt & 1) | ((mt >> 3) << 1);
    int slot = (wE * 4 + g) * 4 + mE;
#pragma unroll
    for (int nt = 0; nt < 4; ++nt) {
      int node = nt * 16 + c;
      ushort4 st;
      st.x = (unsigned short)f2bf(acc[mm][nt][0]);
      st.y = (unsigned short)f2bf(acc[mm][nt][1]);
      st.z = (unsigned short)f2bf(acc[mm][nt][2]);
      st.w = (unsigned short)f2bf(acc[mm][nt][3]);
      outls[node * 64 + (slot ^ ((node & 7) << 3))] = st;
    }
  }
  __syncthreads();
  ushort4* P = half ? P3 : P1;
  for (int i = t; i < 4096; i += 256) {
    int row = i >> 6, slot = i & 63;
    int gn = n0 + row;
    if (gn < NN) P[(size_t)gn * 64 + slot] = outls[row * 64 + (slot ^ ((row & 7) << 3))];
  }
}

// ---------------- ea -> CSR-ordered MFMA B-fragments ----------------
__global__ __launch_bounds__(256) void k_eaprep(const int* __restrict__ eid,
    const float* __restrict__ ea, bf16x8* __restrict__ eaf) {
  int idx = blockIdx.x * 256 + threadIdx.x;
  if (idx >= NTILES * 768) return;
  int tile = idx / 768;
  int r = idx - tile * 768;
  int fr = r >> 6, l = r & 63;
  int nt = fr / 3, ks = fr - 3 * nt;
  int c = l & 15, g = l >> 4;
  int k0 = ks * 32 + g * 8;
  bf16x8 v;
  if (k0 < ED) {
    int e = eid[tile * 64 + nt * 16 + c];
    const float* p = ea + (size_t)e * ED + k0;
    float4 x0 = *(const float4*)p;
    float4 x1 = *(const float4*)(p + 4);
    v[0] = f2bf(x0.x); v[1] = f2bf(x0.y); v[2] = f2bf(x0.z); v[3] = f2bf(x0.w);
    v[4] = f2bf(x1.x); v[5] = f2bf(x1.y); v[6] = f2bf(x1.z); v[7] = f2bf(x1.w);
  } else {
#pragma unroll
    for (int j = 0; j < 8; ++j) v[j] = 0;
  }
  eaf[idx] = v;
}

// ---------------- pass 1: MFMA + gathers + stats + msg; eaf double-buffered ----------------
// Persistent 512-block grid, contiguous tile chunk per block.
// (256,2): VGPR cap 256 — (256,3) spilled (R8). eaf prefetch adds ~48 VGPR.
__global__ __launch_bounds__(256, 2) void k_estat2(
    const int* __restrict__ ssort, const int* __restrict__ dsort,
    const bf16x8* __restrict__ eaf, const unsigned short* __restrict__ Wswz,
    const uint4* __restrict__ P1p, const uint4* __restrict__ P3p,
    ushort4* __restrict__ msgc, float* __restrict__ stats) {
  int t = threadIdx.x;
  int w = t >> 6, l = t & 63;
  int g = l >> 4, c = l & 15;
  int mtg[4] = {2 * w, 2 * w + 1, 2 * w + 8, 2 * w + 9};
  int gi2 = (w * 4 + g) * 2;
  const bf16x8* Wf = (const bf16x8*)Wswz;
  bf16x8 af[4][3];
#pragma unroll
  for (int m = 0; m < 4; ++m)
#pragma unroll
    for (int ks = 0; ks < 3; ++ks) af[m][ks] = Wf[(mtg[m] * 3 + ks) * 64 + l];
  f32x4 ssum[4], ssq[4];
#pragma unroll
  for (int m = 0; m < 4; ++m)
#pragma unroll
    for (int i = 0; i < 4; ++i) { ssum[m][i] = 0.f; ssq[m][i] = 0.f; }

  // contiguous chunk of tiles for this block
  int nblk = gridDim.x;
  int per = (NTILES + nblk - 1) / nblk;
  int t0 = blockIdx.x * per;
  int t1 = min(t0 + per, NTILES);
  if (t0 >= NTILES) return;

  int s_[4], d_[4];
  bf16x8 bcur[12];
#pragma unroll
  for (int nt = 0; nt < 4; ++nt) {
    s_[nt] = ssort[t0 * 64 + nt * 16 + c];
    d_[nt] = dsort[t0 * 64 + nt * 16 + c];
  }
  {
    const bf16x8* bp = eaf + (size_t)t0 * 768 + l;
#pragma unroll
    for (int fr = 0; fr < 12; ++fr) bcur[fr] = bp[fr * 64];
  }
  for (int tile = t0; tile < t1; ++tile) {
    int tn = tile + 1;
    bool more = (tn < t1);
    // burst 1: P gathers for current tile (addresses ready)
    uint4 q1a[4], q1b[4], q3a[4], q3b[4];
#pragma unroll
    for (int nt = 0; nt < 4; ++nt) {
      const uint4* p1 = P1p + (size_t)s_[nt] * 32 + gi2;
      const uint4* p3 = P3p + (size_t)d_[nt] * 32 + gi2;
      q1a[nt] = p1[0];
      q1b[nt] = p1[1];
      q3a[nt] = p3[0];
      q3b[nt] = p3[1];
    }
    // burst 2: next tile's indices
    int sn[4], dn[4];
    int ti = more ? tn : t0;
#pragma unroll
    for (int nt = 0; nt < 4; ++nt) {
      sn[nt] = ssort[ti * 64 + nt * 16 + c];
      dn[nt] = dsort[ti * 64 + nt * 16 + c];
    }
    // burst 3: prefetch next tile's eaf fragments
    bf16x8 bnext[12];
    {
      const bf16x8* bp = eaf + (size_t)ti * 768 + l;
#pragma unroll
      for (int fr = 0; fr < 12; ++fr) bnext[fr] = bp[fr * 64];
    }
    // compute with bcur (ready since previous iteration)
#pragma unroll
    for (int nt = 0; nt < 4; ++nt) {
      f32x4 acc[4];
#pragma unroll
      for (int m = 0; m < 4; ++m) {
        acc[m][0] = 0.f; acc[m][1] = 0.f; acc[m][2] = 0.f; acc[m][3] = 0.f;
      }
#pragma unroll
      for (int ks = 0; ks < 3; ++ks)
#pragma unroll
        for (int m = 0; m < 4; ++m)
          acc[m] = __builtin_amdgcn_mfma_f32_16x16x32_bf16(af[m][ks], bcur[nt * 3 + ks],
                                                           acc[m], 0, 0, 0);
      unsigned pu1[8] = {q1a[nt].x, q1a[nt].y, q1a[nt].z, q1a[nt].w,
                         q1b[nt].x, q1b[nt].y, q1b[nt].z, q1b[nt].w};
      unsigned pu3[8] = {q3a[nt].x, q3a[nt].y, q3a[nt].z, q3a[nt].w,
                         q3b[nt].x, q3b[nt].y, q3b[nt].z, q3b[nt].w};
#pragma unroll
      for (int m = 0; m < 4; ++m) {
        unsigned a1 = pu1[2 * m], b1 = pu1[2 * m + 1];
        unsigned a3 = pu3[2 * m], b3 = pu3[2 * m + 1];
        f32x4 ms;
        ms[0] = acc[m][0] + bflo(a1) + bflo(a3);
        ms[1] = acc[m][1] + bfhi(a1) + bfhi(a3);
        ms[2] = acc[m][2] + bflo(b1) + bflo(b3);
        ms[3] = acc[m][3] + bfhi(b1) + bfhi(b3);
#pragma unroll
        for (int i = 0; i < 4; ++i) {
          ssum[m][i] += ms[i];
          ssq[m][i] = fmaf(ms[i], ms[i], ssq[m][i]);
        }
        ushort4 st;
        st.x = (unsigned short)f2bf(ms[0]);
        st.y = (unsigned short)f2bf(ms[1]);
        st.z = (unsigned short)f2bf(ms[2]);
        st.w = (unsigned short)f2bf(ms[3]);
        msgc[(((size_t)tile * 4 + nt) * 16 + w * 4 + m) * 64 + l] = st;
      }
    }
    // rotate
#pragma unroll
    for (int nt = 0; nt < 4; ++nt) { s_[nt] = sn[nt]; d_[nt] = dn[nt]; }
#pragma unroll
    for (int fr = 0; fr < 12; ++fr) bcur[fr] = bnext[fr];
  }
#pragma unroll
  for (int off = 1; off < 16; off <<= 1)
#pragma unroll
    for (int m = 0; m < 4; ++m)
#pragma unroll
      for (int i = 0; i < 4; ++i) {
        ssum[m][i] += __shfl_xor(ssum[m][i], off, 16);
        ssq[m][i] += __shfl_xor(ssq[m][i], off, 16);
      }
  if (c == 0) {
#pragma unroll
    for (int m = 0; m < 4; ++m)
#pragma unroll
      for (int i = 0; i < 4; ++i) {
        int ch = mtg[m] * 16 + 4 * g + i;
        atomicAdd(&stats[ch], ssum[m][i]);
        atomicAdd(&stats[C2 + ch], ssq[m][i]);
      }
  }
}

// ---------------- pass 2: BN(inline) + gate + DPP segmented scatter ----------------
__global__ __launch_bounds__(256) void k_apply2(
    const int* __restrict__ ssort, const ushort4* __restrict__ msgc,
    const float* __restrict__ st, const float* __restrict__ gammaI,
    const float* __restrict__ betaI, float* __restrict__ agg) {
  int t = threadIdx.x;
  int w = t >> 6, l = t & 63;
  int g = l >> 4, c = l & 15;
  int mtg[4] = {2 * w, 2 * w + 1, 2 * w + 8, 2 * w + 9};
  f32x4 sc4[4], sh4[4];
#pragma unroll
  for (int m = 0; m < 4; ++m)
#pragma unroll
    for (int i = 0; i < 4; ++i) {
      int ch = mtg[m] * 16 + 4 * g + i;
      float mean = st[ch] * (1.f / NE);
      float var = st[C2 + ch] * (1.f / NE) - mean * mean;
      float scv = gammaI[ch] * rsqrtf(var + 1e-5f);
      sc4[m][i] = scv;
      sh4[m][i] = betaI[ch] - mean * scv;
    }
  for (int tile = blockIdx.x; tile < NTILES; tile += gridDim.x) {
    int e0 = tile * 64;
    int s_[4];
#pragma unroll
    for (int nt = 0; nt < 4; ++nt) s_[nt] = ssort[e0 + nt * 16 + c];
    ushort4 mw[4][4];
#pragma unroll
    for (int nt = 0; nt < 4; ++nt)
#pragma unroll
      for (int m = 0; m < 4; ++m)
        mw[nt][m] = msgc[(((size_t)tile * 4 + nt) * 16 + w * 4 + m) * 64 + l];
#pragma unroll
    for (int nt = 0; nt < 4; ++nt) {
      int sv = s_[nt];
      int ps = dpp_i<SHR1>(-1, sv);
      int hp = (ps != sv) ? c : 0;
      hp = max(hp, dpp_i<SHR1>(0, hp));
      hp = max(hp, dpp_i<SHR2>(0, hp));
      hp = max(hp, dpp_i<SHR4>(0, hp));
      hp = max(hp, dpp_i<SHR8>(0, hp));
      int ns = dpp_i<SHL1>(-1, sv);
      bool tail = (ns != sv);
      bool g1 = (c - 1) >= hp, g2 = (c - 2) >= hp, g4 = (c - 4) >= hp, g8 = (c - 8) >= hp;
      f32x4 v4[4];
#pragma unroll
      for (int m = 0; m < 4; ++m) {
        v4[m][0] = fmaf(bf2f(mw[nt][m].x), sc4[m][0], sh4[m][0]);
        v4[m][1] = fmaf(bf2f(mw[nt][m].y), sc4[m][1], sh4[m][1]);
        v4[m][2] = fmaf(bf2f(mw[nt][m].z), sc4[m][2], sh4[m][2]);
        v4[m][3] = fmaf(bf2f(mw[nt][m].w), sc4[m][3], sh4[m][3]);
      }
      float gg_[8];
#pragma unroll
      for (int p = 0; p < 2; ++p)
#pragma unroll
        for (int i = 0; i < 4; ++i)
          gg_[p * 4 + i] = gate_(v4[p][i], v4[p + 2][i]);
#pragma unroll
      for (int q = 0; q < 8; ++q) {
        float tv;
        tv = dpp_f<SHR1>(0.f, gg_[q]); gg_[q] += g1 ? tv : 0.f;
        tv = dpp_f<SHR2>(0.f, gg_[q]); gg_[q] += g2 ? tv : 0.f;
        tv = dpp_f<SHR4>(0.f, gg_[q]); gg_[q] += g4 ? tv : 0.f;
        tv = dpp_f<SHR8>(0.f, gg_[q]); gg_[q] += g8 ? tv : 0.f;
      }
      if (tail) {
#pragma unroll
        for (int p = 0; p < 2; ++p)
#pragma unroll
          for (int i = 0; i < 4; ++i)
            atomicAdd(&agg[(size_t)sv * HD + mtg[p] * 16 + 4 * g + i], gg_[p * 4 + i]);
      }
    }
  }
}

// ---------------- agg BN stats ----------------
__global__ __launch_bounds__(256) void k_aggstat(const float* __restrict__ agg,
                                                 float* __restrict__ stats) {
  int t = threadIdx.x;
  int c = t & 127, half = t >> 7;
  float s = 0.f, sq = 0.f;
  for (int n = blockIdx.x * 2 + half; n < NN; n += gridDim.x * 2) {
    float v = agg[(size_t)n * HD + c];
    s += v;
    sq = fmaf(v, v, sq);
  }
  __shared__ float shs[2][128], shq[2][128];
  shs[half][c] = s;
  shq[half][c] = sq;
  __syncthreads();
  if (t < 128) {
    atomicAdd(&stats[c], shs[0][c] + shs[1][c]);
    atomicAdd(&stats[128 + c], shq[0][c] + shq[1][c]);
  }
}

// ---------------- h update (BN inline) ----------------
__global__ __launch_bounds__(256) void k_update(const float* __restrict__ h,
    const float* __restrict__ agg, const float* __restrict__ st_o,
    const float* __restrict__ bog, const float* __restrict__ bob,
    float* __restrict__ hn, unsigned short* __restrict__ hbf) {
  int stride = gridDim.x * 256;
  for (int i = blockIdx.x * 256 + threadIdx.x; i < NN * HD; i += stride) {
    int c = i & 127;
    float mean = st_o[c] * (1.f / NN);
    float var = st_o[128 + c] * (1.f / NN) - mean * mean;
    float scv = bog[c] * rsqrtf(var + 1e-5f);
    float shv = bob[c] - mean * scv;
    float v = h[i] + fmaf(agg[i], scv, shv);
    float r = softplusf_(v);
    hn[i] = r;
    hbf[i] = (unsigned short)f2bf(r);
  }
}

// ---------------- pooling ----------------
__global__ __launch_bounds__(256) void k_pool(const float* __restrict__ h,
    const int* __restrict__ batch, float* __restrict__ psum, int* __restrict__ pcnt) {
  int stride = gridDim.x * 256;
  for (int i = blockIdx.x * 256 + threadIdx.x; i < NN * HD; i += stride) {
    int n = i >> 7, c = i & 127;
    int g = batch[n];
    atomicAdd(&psum[g * HD + c], h[i]);
    if (c == 0) atomicAdd(&pcnt[g], 1);
  }
}

// ---------------- head ----------------
__global__ __launch_bounds__(128) void k_head(const float* __restrict__ psum,
    const int* __restrict__ pcnt, const float* __restrict__ linW,
    const float* __restrict__ linb, const float* __restrict__ outW,
    const float* __restrict__ outb, float* __restrict__ out) {
  __shared__ float pl[HD];
  __shared__ float red[2];
  int g = blockIdx.x, t = threadIdx.x;
  float cnt = fmaxf((float)pcnt[g], 1.f);
  pl[t] = psum[g * HD + t] / cnt;
  __syncthreads();
  float acc = linb[t];
  for (int k = 0; k < HD; ++k) acc = fmaf(pl[k], linW[k * HD + t], acc);
  float term = softplusf_(acc) * outW[t];
#pragma unroll
  for (int off = 32; off > 0; off >>= 1) term += __shfl_down(term, off, 64);
  if ((t & 63) == 0) red[t >> 6] = term;
  __syncthreads();
  if (t == 0) out[g] = red[0] + red[1] + outb[0];
}

extern "C" void kernel_launch(void* const* d_in, const int* in_sizes, int n_in,
                              void* d_out, int out_size, void* d_ws, size_t ws_size,
                              hipStream_t stream) {
  const float* x = (const float*)d_in[0];
  const int* ei = (const int*)d_in[1];
  const float* ea = (const float*)d_in[2];
  const int* batch = (const int*)d_in[3];
  const float* embW = (const float*)d_in[4];
  const float* embb = (const float*)d_in[5];
  const float* convW = (const float*)d_in[6];
  // convb cancels inside BN — unused.
  const float* big = (const float*)d_in[8];
  const float* bib = (const float*)d_in[9];
  const float* bog = (const float*)d_in[10];
  const float* bob = (const float*)d_in[11];
  const float* linW = (const float*)d_in[12];
  const float* linb = (const float*)d_in[13];
  const float* outW = (const float*)d_in[14];
  const float* outb = (const float*)d_in[15];
  float* out = (float*)d_out;

  float* wsf = (float*)d_ws;
  size_t off = 0;
  auto alloc = [&](size_t n) {
    float* p = wsf + off;
    off += (n + 3) & ~(size_t)3;
    return p;
  };
  float* h0 = alloc((size_t)NN * HD);
  float* h1 = alloc((size_t)NN * HD);
  unsigned short* hbf = (unsigned short*)alloc((size_t)NN * HD / 2);
  ushort4* P1b = (ushort4*)alloc((size_t)NN * C2 / 2);
  ushort4* P3b = (ushort4*)alloc((size_t)NN * C2 / 2);
  float* agg = alloc((size_t)NN * HD);
  float* st_i = alloc(2 * C2);
  float* st_o = alloc(2 * HD);
  float* psum = alloc((size_t)NG * HD);
  int* pcnt = (int*)alloc(NG);
  int* deg = (int*)alloc(NN);
  int* cursor = (int*)alloc(NN);
  int* eid = (int*)alloc(NE);
  int* ssort = (int*)alloc(NE);
  int* dsort = (int*)alloc(NE);
  unsigned short* Wswz = (unsigned short*)alloc((NC * WSZ_L + 1) / 2);
  unsigned short* Wn = (unsigned short*)alloc((NC * 2 * WNP_L + 1) / 2);
  bf16x8* eaf = (bf16x8*)alloc((size_t)NTILES * 768 * 4);
  ushort4* msgc = (ushort4*)alloc((size_t)NE * C2 / 2);

  const int* srcp = ei;
  const int* dstp = ei + NE;

  hipMemsetAsync(deg, 0, NN * sizeof(int), stream);
  k_hist<<<2048, 256, 0, stream>>>(srcp, deg);
  k_scan<<<1, 1024, 0, stream>>>(deg, cursor);
  k_scatter<<<2048, 256, 0, stream>>>(srcp, dstp, cursor, eid, ssort, dsort);

  k_wprep<<<(NC * WSZ_L + 255) / 256, 256, 0, stream>>>(convW, Wswz);
  k_wprep2<<<(NC * 2 * WNP_L + 255) / 256, 256, 0, stream>>>(convW, Wn);
  k_eaprep<<<(NTILES * 768 + 255) / 256, 256, 0, stream>>>(eid, ea, eaf);
  k_embed<<<NN / 2, 256, 0, stream>>>(x, embW, embb, h0, hbf);

  float* hc = h0;
  float* hn = h1;
  for (int L = 0; L < NC; ++L) {
    const unsigned short* Wl = Wswz + (size_t)L * WSZ_L;
    hipMemsetAsync(st_i, 0, 2 * C2 * sizeof(float), stream);
    hipMemsetAsync(st_o, 0, 2 * HD * sizeof(float), stream);
    hipMemsetAsync(agg, 0, (size_t)NN * HD * sizeof(float), stream);

    dim3 npgrid((NN + 63) / 64, 2);
    k_nodeproj2<<<npgrid, 256, 0, stream>>>(hbf, Wn, L, P1b, P3b);
    k_estat2<<<512, 256, 0, stream>>>(ssort, dsort, eaf, Wl,
        (const uint4*)P1b, (const uint4*)P3b, msgc, st_i);
    k_apply2<<<2500, 256, 0, stream>>>(ssort, msgc, st_i, big + L * C2, bib + L * C2, agg);
    k_aggstat<<<512, 256, 0, stream>>>(agg, st_o);
    k_update<<<2048, 256, 0, stream>>>(hc, agg, st_o, bog + L * HD, bob + L * HD, hn, hbf);
    float* tmp = hc; hc = hn; hn = tmp;
  }

  hipMemsetAsync(psum, 0, (size_t)NG * HD * sizeof(float), stream);
  hipMemsetAsync(pcnt, 0, NG * sizeof(int), stream);
  k_pool<<<2048, 256, 0, stream>>>(hc, batch, psum, pcnt);
  k_head<<<NG, 128, 0, stream>>>(psum, pcnt, linW, linb, outW, outb, out);
}

// Round 11
// 2235.324 us; speedup vs baseline: 1.0840x; 1.0840x over previous
//
#include <hip/hip_runtime.h>

constexpr int NN = 50000;
constexpr int NE = 800000;
constexpr int XD = 92;
constexpr int ED = 80;
constexpr int HD = 128;
constexpr int C2 = 256;   // 2*HD
constexpr int IND = 336;  // 2*HD + ED
constexpr int NC = 3;
constexpr int NG = 256;
constexpr int NTILES = NE / 64;      // 12500
constexpr int WSZ_L = 16 * 3 * 64 * 8;   // per-layer swizzled W2 frags (ushort)
constexpr int WNP_L = 16 * 4 * 64 * 8;   // per-(layer,half) nodeproj W frags

#define DINL __device__ __forceinline__

typedef __attribute__((ext_vector_type(8))) short bf16x8;
typedef __attribute__((ext_vector_type(4))) float f32x4;

DINL short f2bf(float f) {
  unsigned u = __float_as_uint(f);
  u = (u + 0x7fffu + ((u >> 16) & 1u)) >> 16;
  return (short)u;
}
DINL float bf2f(unsigned short u) { return __uint_as_float(((unsigned)u) << 16); }
DINL float bflo(unsigned u) { return __uint_as_float(u << 16); }
DINL float bfhi(unsigned u) { return __uint_as_float(u & 0xffff0000u); }
DINL float rcp_(float x) {
  float r;
  asm("v_rcp_f32 %0, %1" : "=v"(r) : "v"(x));
  return r;
}
DINL float softplusf_(float x) { return x > 20.f ? x : log1pf(__expf(x)); }
DINL float gate_(float f, float cr) {
  float e = __expf(-f);
  float s = rcp_(1.f + e);
  float t = __expf(cr);
  float l = (cr > 15.f) ? cr : __logf(1.f + t);
  return s * l;
}

template <int CTRL>
DINL int dpp_i(int old_, int src) {
  return __builtin_amdgcn_update_dpp(old_, src, CTRL, 0xF, 0xF, false);
}
template <int CTRL>
DINL float dpp_f(float old_, float src) {
  return __int_as_float(
      __builtin_amdgcn_update_dpp(__float_as_int(old_), __float_as_int(src), CTRL, 0xF, 0xF, false));
}
constexpr int SHR1 = 0x111, SHR2 = 0x112, SHR4 = 0x114, SHR8 = 0x118, SHL1 = 0x101;

// ---------------- embed ----------------
__global__ __launch_bounds__(256) void k_embed(const float* __restrict__ x,
    const float* __restrict__ W, const float* __restrict__ b, float* __restrict__ h,
    unsigned short* __restrict__ hbf) {
  __shared__ float xs[2][XD];
  int t = threadIdx.x;
  int n0 = blockIdx.x * 2;
  for (int i = t; i < 2 * XD; i += 256) xs[i / XD][i % XD] = x[(size_t)n0 * XD + i];
  __syncthreads();
  int lo = t >> 7, c = t & 127;
  float acc = b[c];
  for (int k = 0; k < XD; ++k) acc = fmaf(xs[lo][k], W[k * HD + c], acc);
  h[(size_t)(n0 + lo) * HD + c] = acc;
  hbf[(size_t)(n0 + lo) * HD + c] = (unsigned short)f2bf(acc);
}

// ---------------- CSR build ----------------
__global__ __launch_bounds__(256) void k_hist(const int* __restrict__ src,
                                              int* __restrict__ deg) {
  for (int e = blockIdx.x * 256 + threadIdx.x; e < NE; e += gridDim.x * 256)
    atomicAdd(&deg[src[e]], 1);
}

__global__ __launch_bounds__(1024) void k_scan(const int* __restrict__ deg,
                                               int* __restrict__ cursor) {
  __shared__ int sums[1024];
  int t = threadIdx.x;
  const int CH = 49;
  int b0 = t * CH;
  int s = 0;
  for (int i = 0; i < CH; ++i) {
    int idx = b0 + i;
    if (idx < NN) s += deg[idx];
  }
  sums[t] = s;
  __syncthreads();
  for (int off = 1; off < 1024; off <<= 1) {
    int v = (t >= off) ? sums[t - off] : 0;
    __syncthreads();
    sums[t] += v;
    __syncthreads();
  }
  int excl = (t == 0) ? 0 : sums[t - 1];
  for (int i = 0; i < CH; ++i) {
    int idx = b0 + i;
    if (idx < NN) {
      cursor[idx] = excl;
      excl += deg[idx];
    }
  }
}

__global__ __launch_bounds__(256) void k_scatter(const int* __restrict__ src,
    const int* __restrict__ dst, int* __restrict__ cursor, int* __restrict__ eid,
    int* __restrict__ ssort, int* __restrict__ dsort) {
  for (int e = blockIdx.x * 256 + threadIdx.x; e < NE; e += gridDim.x * 256) {
    int s = src[e];
    int pos = atomicAdd(&cursor[s], 1);
    eid[pos] = e;
    ssort[pos] = s;
    dsort[pos] = dst[e];
  }
}

// ---------------- W2 -> edge-GEMM MFMA fragments ----------------
__global__ __launch_bounds__(256) void k_wprep(const float* __restrict__ convW,
                                               unsigned short* __restrict__ Wswz) {
  int idx = blockIdx.x * 256 + threadIdx.x;
  if (idx >= NC * WSZ_L) return;
  int L = idx / WSZ_L;
  int rem = idx - L * WSZ_L;
  int mt = rem / 1536;
  int rem2 = rem - mt * 1536;
  int ks = rem2 >> 9;
  int lane = (rem2 >> 3) & 63;
  int j = rem2 & 7;
  int k = ks * 32 + (lane >> 4) * 8 + j;
  int m = mt * 16 + (lane & 15);
  float v = (k < ED) ? convW[(size_t)L * IND * C2 + (size_t)(HD + k) * C2 + m] : 0.f;
  Wswz[idx] = (unsigned short)f2bf(v);
}

// ---------------- W1/W3 -> nodeproj MFMA fragments ----------------
__global__ __launch_bounds__(256) void k_wprep2(const float* __restrict__ convW,
                                                unsigned short* __restrict__ Wn) {
  int idx = blockIdx.x * 256 + threadIdx.x;
  if (idx >= NC * 2 * WNP_L) return;
  int Lh = idx >> 15;
  int L = Lh >> 1, half = Lh & 1;
  int rem = idx & 32767;
  int mt = rem >> 11;
  int rem2 = rem & 2047;
  int ks = rem2 >> 9;
  int lane = (rem2 >> 3) & 63;
  int j = rem2 & 7;
  int k = ks * 32 + (lane >> 4) * 8 + j;
  int m = mt * 16 + (lane & 15);
  int row = (half ? 208 : 0) + k;
  Wn[idx] = (unsigned short)f2bf(convW[(size_t)L * IND * C2 + (size_t)row * C2 + m]);
}

// ---------------- nodeproj via MFMA; output in PERMUTED slot layout ----------------
// slot(mt,g) = (wE*4+g)*4 + mE with wE=(mt&7)>>1, mE=(mt&1)|((mt>>3)<<1)
// => estat2 thread (w,g) reads slots (w*4+g)*4 .. +3 = contiguous 32B.
__global__ __launch_bounds__(256) void k_nodeproj2(const unsigned short* __restrict__ hbf,
    const unsigned short* __restrict__ Wn, int L,
    ushort4* __restrict__ P1, ushort4* __restrict__ P3) {
  __shared__ bf16x8 hls[1024];
  __shared__ ushort4 outls[4096];
  int t = threadIdx.x, w = t >> 6, l = t & 63, g = l >> 4, c = l & 15;
  int n0 = blockIdx.x * 64;
  int half = blockIdx.y;
  for (int i = t; i < 1024; i += 256) {
    int node = i >> 4, chunk = i & 15;
    int gn = n0 + node;
    if (gn >= NN) gn = NN - 1;
    bf16x8 v = *(const bf16x8*)(hbf + (size_t)gn * HD + chunk * 8);
    hls[node * 16 + (chunk ^ (node & 7))] = v;
  }
  __syncthreads();
  const bf16x8* Wf = (const bf16x8*)(Wn + ((size_t)(L * 2 + half)) * WNP_L);
  bf16x8 af[4][4];
#pragma unroll
  for (int mm = 0; mm < 4; ++mm)
#pragma unroll
    for (int ks = 0; ks < 4; ++ks) af[mm][ks] = Wf[((w * 4 + mm) * 4 + ks) * 64 + l];
  f32x4 acc[4][4];
#pragma unroll
  for (int mm = 0; mm < 4; ++mm)
#pragma unroll
    for (int nt = 0; nt < 4; ++nt)
#pragma unroll
      for (int i = 0; i < 4; ++i) acc[mm][nt][i] = 0.f;
#pragma unroll
  for (int nt = 0; nt < 4; ++nt) {
    int node = nt * 16 + c;
#pragma unroll
    for (int ks = 0; ks < 4; ++ks) {
      bf16x8 b = hls[node * 16 + ((4 * ks + g) ^ (node & 7))];
#pragma unroll
      for (int mm = 0; mm < 4; ++mm)
        acc[mm][nt] = __builtin_amdgcn_mfma_f32_16x16x32_bf16(af[mm][ks], b, acc[mm][nt], 0, 0, 0);
    }
  }
  __syncthreads();
#pragma unroll
  for (int mm = 0; mm < 4; ++mm) {
    int mt = w * 4 + mm;
    int wE = (mt & 7) >> 1;
    int mE = (mt & 1) | ((mt >> 3) << 1);
    int slot = (wE * 4 + g) * 4 + mE;
#pragma unroll
    for (int nt = 0; nt < 4; ++nt) {
      int node = nt * 16 + c;
      ushort4 st;
      st.x = (unsigned short)f2bf(acc[mm][nt][0]);
      st.y = (unsigned short)f2bf(acc[mm][nt][1]);
      st.z = (unsigned short)f2bf(acc[mm][nt][2]);
      st.w = (unsigned short)f2bf(acc[mm][nt][3]);
      outls[node * 64 + (slot ^ ((node & 7) << 3))] = st;
    }
  }
  __syncthreads();
  ushort4* P = half ? P3 : P1;
  for (int i = t; i < 4096; i += 256) {
    int row = i >> 6, slot = i & 63;
    int gn = n0 + row;
    if (gn < NN) P[(size_t)gn * 64 + slot] = outls[row * 64 + (slot ^ ((row & 7) << 3))];
  }
}

// ---------------- ea -> CSR-ordered MFMA B-fragments ----------------
__global__ __launch_bounds__(256) void k_eaprep(const int* __restrict__ eid,
    const float* __restrict__ ea, bf16x8* __restrict__ eaf) {
  int idx = blockIdx.x * 256 + threadIdx.x;
  if (idx >= NTILES * 768) return;
  int tile = idx / 768;
  int r = idx - tile * 768;
  int fr = r >> 6, l = r & 63;
  int nt = fr / 3, ks = fr - 3 * nt;
  int c = l & 15, g = l >> 4;
  int k0 = ks * 32 + g * 8;
  bf16x8 v;
  if (k0 < ED) {
    int e = eid[tile * 64 + nt * 16 + c];
    const float* p = ea + (size_t)e * ED + k0;
    float4 x0 = *(const float4*)p;
    float4 x1 = *(const float4*)(p + 4);
    v[0] = f2bf(x0.x); v[1] = f2bf(x0.y); v[2] = f2bf(x0.z); v[3] = f2bf(x0.w);
    v[4] = f2bf(x1.x); v[5] = f2bf(x1.y); v[6] = f2bf(x1.z); v[7] = f2bf(x1.w);
  } else {
#pragma unroll
    for (int j = 0; j < 8; ++j) v[j] = 0;
  }
  eaf[idx] = v;
}

// ---------------- pass 1 (pipelined): MFMA + 32B-contiguous gathers + stats + msg ----------------
// R9-proven version: no register double-buffer (spills — R10), (256,2), 2500-block grid-stride.
__global__ __launch_bounds__(256, 2) void k_estat2(
    const int* __restrict__ ssort, const int* __restrict__ dsort,
    const bf16x8* __restrict__ eaf, const unsigned short* __restrict__ Wswz,
    const uint4* __restrict__ P1p, const uint4* __restrict__ P3p,
    ushort4* __restrict__ msgc, float* __restrict__ stats) {
  int t = threadIdx.x;
  int w = t >> 6, l = t & 63;
  int g = l >> 4, c = l & 15;
  int mtg[4] = {2 * w, 2 * w + 1, 2 * w + 8, 2 * w + 9};
  int gi2 = (w * 4 + g) * 2;
  const bf16x8* Wf = (const bf16x8*)Wswz;
  bf16x8 af[4][3];
#pragma unroll
  for (int m = 0; m < 4; ++m)
#pragma unroll
    for (int ks = 0; ks < 3; ++ks) af[m][ks] = Wf[(mtg[m] * 3 + ks) * 64 + l];
  f32x4 ssum[4], ssq[4];
#pragma unroll
  for (int m = 0; m < 4; ++m)
#pragma unroll
    for (int i = 0; i < 4; ++i) { ssum[m][i] = 0.f; ssq[m][i] = 0.f; }

  const int stride = gridDim.x;
  int tile = blockIdx.x;
  int s_[4], d_[4];
  if (tile < NTILES) {
#pragma unroll
    for (int nt = 0; nt < 4; ++nt) {
      s_[nt] = ssort[tile * 64 + nt * 16 + c];
      d_[nt] = dsort[tile * 64 + nt * 16 + c];
    }
  }
  for (; tile < NTILES; tile += stride) {
    // burst 1: eaf fragments (linear)
    bf16x8 b_[12];
    const bf16x8* bp = eaf + (size_t)tile * 768 + l;
#pragma unroll
    for (int fr = 0; fr < 12; ++fr) b_[fr] = bp[fr * 64];
    // burst 2: P gathers — 2 x 16B contiguous per P per nt (node stride = 32 uint4)
    uint4 q1a[4], q1b[4], q3a[4], q3b[4];
#pragma unroll
    for (int nt = 0; nt < 4; ++nt) {
      const uint4* p1 = P1p + (size_t)s_[nt] * 32 + gi2;
      const uint4* p3 = P3p + (size_t)d_[nt] * 32 + gi2;
      q1a[nt] = p1[0];
      q1b[nt] = p1[1];
      q3a[nt] = p3[0];
      q3b[nt] = p3[1];
    }
    // burst 3: next tile's indices
    int sn[4], dn[4];
    int tn = tile + stride;
    if (tn < NTILES) {
#pragma unroll
      for (int nt = 0; nt < 4; ++nt) {
        sn[nt] = ssort[tn * 64 + nt * 16 + c];
        dn[nt] = dsort[tn * 64 + nt * 16 + c];
      }
    } else {
#pragma unroll
      for (int nt = 0; nt < 4; ++nt) { sn[nt] = 0; dn[nt] = 0; }
    }
    // compute
#pragma unroll
    for (int nt = 0; nt < 4; ++nt) {
      f32x4 acc[4];
#pragma unroll
      for (int m = 0; m < 4; ++m) {
        acc[m][0] = 0.f; acc[m][1] = 0.f; acc[m][2] = 0.f; acc[m][3] = 0.f;
      }
#pragma unroll
      for (int ks = 0; ks < 3; ++ks)
#pragma unroll
        for (int m = 0; m < 4; ++m)
          acc[m] = __builtin_amdgcn_mfma_f32_16x16x32_bf16(af[m][ks], b_[nt * 3 + ks],
                                                           acc[m], 0, 0, 0);
      unsigned pu1[8] = {q1a[nt].x, q1a[nt].y, q1a[nt].z, q1a[nt].w,
                         q1b[nt].x, q1b[nt].y, q1b[nt].z, q1b[nt].w};
      unsigned pu3[8] = {q3a[nt].x, q3a[nt].y, q3a[nt].z, q3a[nt].w,
                         q3b[nt].x, q3b[nt].y, q3b[nt].z, q3b[nt].w};
#pragma unroll
      for (int m = 0; m < 4; ++m) {
        unsigned a1 = pu1[2 * m], b1 = pu1[2 * m + 1];
        unsigned a3 = pu3[2 * m], b3 = pu3[2 * m + 1];
        f32x4 ms;
        ms[0] = acc[m][0] + bflo(a1) + bflo(a3);
        ms[1] = acc[m][1] + bfhi(a1) + bfhi(a3);
        ms[2] = acc[m][2] + bflo(b1) + bflo(b3);
        ms[3] = acc[m][3] + bfhi(b1) + bfhi(b3);
#pragma unroll
        for (int i = 0; i < 4; ++i) {
          ssum[m][i] += ms[i];
          ssq[m][i] = fmaf(ms[i], ms[i], ssq[m][i]);
        }
        ushort4 st;
        st.x = (unsigned short)f2bf(ms[0]);
        st.y = (unsigned short)f2bf(ms[1]);
        st.z = (unsigned short)f2bf(ms[2]);
        st.w = (unsigned short)f2bf(ms[3]);
        msgc[(((size_t)tile * 4 + nt) * 16 + w * 4 + m) * 64 + l] = st;
      }
    }
#pragma unroll
    for (int nt = 0; nt < 4; ++nt) { s_[nt] = sn[nt]; d_[nt] = dn[nt]; }
  }
#pragma unroll
  for (int off = 1; off < 16; off <<= 1)
#pragma unroll
    for (int m = 0; m < 4; ++m)
#pragma unroll
      for (int i = 0; i < 4; ++i) {
        ssum[m][i] += __shfl_xor(ssum[m][i], off, 16);
        ssq[m][i] += __shfl_xor(ssq[m][i], off, 16);
      }
  if (c == 0) {
#pragma unroll
    for (int m = 0; m < 4; ++m)
#pragma unroll
      for (int i = 0; i < 4; ++i) {
        int ch = mtg[m] * 16 + 4 * g + i;
        atomicAdd(&stats[ch], ssum[m][i]);
        atomicAdd(&stats[C2 + ch], ssq[m][i]);
      }
  }
}

// ---------------- pass 2: BN(inline) + gate + DPP scatter; msgc/ssort one-ahead prefetch ----------------
__global__ __launch_bounds__(256) void k_apply2(
    const int* __restrict__ ssort, const ushort4* __restrict__ msgc,
    const float* __restrict__ st, const float* __restrict__ gammaI,
    const float* __restrict__ betaI, float* __restrict__ agg) {
  int t = threadIdx.x;
  int w = t >> 6, l = t & 63;
  int g = l >> 4, c = l & 15;
  int mtg[4] = {2 * w, 2 * w + 1, 2 * w + 8, 2 * w + 9};
  f32x4 sc4[4], sh4[4];
#pragma unroll
  for (int m = 0; m < 4; ++m)
#pragma unroll
    for (int i = 0; i < 4; ++i) {
      int ch = mtg[m] * 16 + 4 * g + i;
      float mean = st[ch] * (1.f / NE);
      float var = st[C2 + ch] * (1.f / NE) - mean * mean;
      float scv = gammaI[ch] * rsqrtf(var + 1e-5f);
      sc4[m][i] = scv;
      sh4[m][i] = betaI[ch] - mean * scv;
    }
  const int stride = gridDim.x;
  int tile = blockIdx.x;
  if (tile >= NTILES) return;
  int s_[4];
  ushort4 mw[4][4];
#pragma unroll
  for (int nt = 0; nt < 4; ++nt) {
    s_[nt] = ssort[tile * 64 + nt * 16 + c];
#pragma unroll
    for (int m = 0; m < 4; ++m)
      mw[nt][m] = msgc[(((size_t)tile * 4 + nt) * 16 + w * 4 + m) * 64 + l];
  }
  for (; tile < NTILES; tile += stride) {
    // prefetch next tile's indices + msg quads (hidden under this tile's VALU work)
    int tn = tile + stride;
    int ti = (tn < NTILES) ? tn : tile;
    int sn[4];
    ushort4 mwn[4][4];
#pragma unroll
    for (int nt = 0; nt < 4; ++nt) {
      sn[nt] = ssort[ti * 64 + nt * 16 + c];
#pragma unroll
      for (int m = 0; m < 4; ++m)
        mwn[nt][m] = msgc[(((size_t)ti * 4 + nt) * 16 + w * 4 + m) * 64 + l];
    }
    // compute on current tile
#pragma unroll
    for (int nt = 0; nt < 4; ++nt) {
      int sv = s_[nt];
      int ps = dpp_i<SHR1>(-1, sv);
      int hp = (ps != sv) ? c : 0;
      hp = max(hp, dpp_i<SHR1>(0, hp));
      hp = max(hp, dpp_i<SHR2>(0, hp));
      hp = max(hp, dpp_i<SHR4>(0, hp));
      hp = max(hp, dpp_i<SHR8>(0, hp));
      int ns = dpp_i<SHL1>(-1, sv);
      bool tail = (ns != sv);
      bool g1 = (c - 1) >= hp, g2 = (c - 2) >= hp, g4 = (c - 4) >= hp, g8 = (c - 8) >= hp;
      f32x4 v4[4];
#pragma unroll
      for (int m = 0; m < 4; ++m) {
        v4[m][0] = fmaf(bf2f(mw[nt][m].x), sc4[m][0], sh4[m][0]);
        v4[m][1] = fmaf(bf2f(mw[nt][m].y), sc4[m][1], sh4[m][1]);
        v4[m][2] = fmaf(bf2f(mw[nt][m].z), sc4[m][2], sh4[m][2]);
        v4[m][3] = fmaf(bf2f(mw[nt][m].w), sc4[m][3], sh4[m][3]);
      }
      float gg_[8];
#pragma unroll
      for (int p = 0; p < 2; ++p)
#pragma unroll
        for (int i = 0; i < 4; ++i)
          gg_[p * 4 + i] = gate_(v4[p][i], v4[p + 2][i]);
#pragma unroll
      for (int q = 0; q < 8; ++q) {
        float tv;
        tv = dpp_f<SHR1>(0.f, gg_[q]); gg_[q] += g1 ? tv : 0.f;
        tv = dpp_f<SHR2>(0.f, gg_[q]); gg_[q] += g2 ? tv : 0.f;
        tv = dpp_f<SHR4>(0.f, gg_[q]); gg_[q] += g4 ? tv : 0.f;
        tv = dpp_f<SHR8>(0.f, gg_[q]); gg_[q] += g8 ? tv : 0.f;
      }
      if (tail) {
#pragma unroll
        for (int p = 0; p < 2; ++p)
#pragma unroll
          for (int i = 0; i < 4; ++i)
            atomicAdd(&agg[(size_t)sv * HD + mtg[p] * 16 + 4 * g + i], gg_[p * 4 + i]);
      }
    }
    // rotate
#pragma unroll
    for (int nt = 0; nt < 4; ++nt) {
      s_[nt] = sn[nt];
#pragma unroll
      for (int m = 0; m < 4; ++m) mw[nt][m] = mwn[nt][m];
    }
  }
}

// ---------------- agg BN stats ----------------
__global__ __launch_bounds__(256) void k_aggstat(const float* __restrict__ agg,
                                                 float* __restrict__ stats) {
  int t = threadIdx.x;
  int c = t & 127, half = t >> 7;
  float s = 0.f, sq = 0.f;
  for (int n = blockIdx.x * 2 + half; n < NN; n += gridDim.x * 2) {
    float v = agg[(size_t)n * HD + c];
    s += v;
    sq = fmaf(v, v, sq);
  }
  __shared__ float shs[2][128], shq[2][128];
  shs[half][c] = s;
  shq[half][c] = sq;
  __syncthreads();
  if (t < 128) {
    atomicAdd(&stats[c], shs[0][c] + shs[1][c]);
    atomicAdd(&stats[128 + c], shq[0][c] + shq[1][c]);
  }
}

// ---------------- h update (BN inline) ----------------
__global__ __launch_bounds__(256) void k_update(const float* __restrict__ h,
    const float* __restrict__ agg, const float* __restrict__ st_o,
    const float* __restrict__ bog, const float* __restrict__ bob,
    float* __restrict__ hn, unsigned short* __restrict__ hbf) {
  int stride = gridDim.x * 256;
  for (int i = blockIdx.x * 256 + threadIdx.x; i < NN * HD; i += stride) {
    int c = i & 127;
    float mean = st_o[c] * (1.f / NN);
    float var = st_o[128 + c] * (1.f / NN) - mean * mean;
    float scv = bog[c] * rsqrtf(var + 1e-5f);
    float shv = bob[c] - mean * scv;
    float v = h[i] + fmaf(agg[i], scv, shv);
    float r = softplusf_(v);
    hn[i] = r;
    hbf[i] = (unsigned short)f2bf(r);
  }
}

// ---------------- pooling ----------------
__global__ __launch_bounds__(256) void k_pool(const float* __restrict__ h,
    const int* __restrict__ batch, float* __restrict__ psum, int* __restrict__ pcnt) {
  int stride = gridDim.x * 256;
  for (int i = blockIdx.x * 256 + threadIdx.x; i < NN * HD; i += stride) {
    int n = i >> 7, c = i & 127;
    int g = batch[n];
    atomicAdd(&psum[g * HD + c], h[i]);
    if (c == 0) atomicAdd(&pcnt[g], 1);
  }
}

// ---------------- head ----------------
__global__ __launch_bounds__(128) void k_head(const float* __restrict__ psum,
    const int* __restrict__ pcnt, const float* __restrict__ linW,
    const float* __restrict__ linb, const float* __restrict__ outW,
    const float* __restrict__ outb, float* __restrict__ out) {
  __shared__ float pl[HD];
  __shared__ float red[2];
  int g = blockIdx.x, t = threadIdx.x;
  float cnt = fmaxf((float)pcnt[g], 1.f);
  pl[t] = psum[g * HD + t] / cnt;
  __syncthreads();
  float acc = linb[t];
  for (int k = 0; k < HD; ++k) acc = fmaf(pl[k], linW[k * HD + t], acc);
  float term = softplusf_(acc) * outW[t];
#pragma unroll
  for (int off = 32; off > 0; off >>= 1) term += __shfl_down(term, off, 64);
  if ((t & 63) == 0) red[t >> 6] = term;
  __syncthreads();
  if (t == 0) out[g] = red[0] + red[1] + outb[0];
}

extern "C" void kernel_launch(void* const* d_in, const int* in_sizes, int n_in,
                              void* d_out, int out_size, void* d_ws, size_t ws_size,
                              hipStream_t stream) {
  const float* x = (const float*)d_in[0];
  const int* ei = (const int*)d_in[1];
  const float* ea = (const float*)d_in[2];
  const int* batch = (const int*)d_in[3];
  const float* embW = (const float*)d_in[4];
  const float* embb = (const float*)d_in[5];
  const float* convW = (const float*)d_in[6];
  // convb cancels inside BN — unused.
  const float* big = (const float*)d_in[8];
  const float* bib = (const float*)d_in[9];
  const float* bog = (const float*)d_in[10];
  const float* bob = (const float*)d_in[11];
  const float* linW = (const float*)d_in[12];
  const float* linb = (const float*)d_in[13];
  const float* outW = (const float*)d_in[14];
  const float* outb = (const float*)d_in[15];
  float* out = (float*)d_out;

  float* wsf = (float*)d_ws;
  size_t off = 0;
  auto alloc = [&](size_t n) {
    float* p = wsf + off;
    off += (n + 3) & ~(size_t)3;
    return p;
  };
  float* h0 = alloc((size_t)NN * HD);
  float* h1 = alloc((size_t)NN * HD);
  unsigned short* hbf = (unsigned short*)alloc((size_t)NN * HD / 2);
  ushort4* P1b = (ushort4*)alloc((size_t)NN * C2 / 2);
  ushort4* P3b = (ushort4*)alloc((size_t)NN * C2 / 2);
  float* agg = alloc((size_t)NN * HD);
  float* st_i = alloc(2 * C2);
  float* st_o = alloc(2 * HD);
  float* psum = alloc((size_t)NG * HD);
  int* pcnt = (int*)alloc(NG);
  int* deg = (int*)alloc(NN);
  int* cursor = (int*)alloc(NN);
  int* eid = (int*)alloc(NE);
  int* ssort = (int*)alloc(NE);
  int* dsort = (int*)alloc(NE);
  unsigned short* Wswz = (unsigned short*)alloc((NC * WSZ_L + 1) / 2);
  unsigned short* Wn = (unsigned short*)alloc((NC * 2 * WNP_L + 1) / 2);
  bf16x8* eaf = (bf16x8*)alloc((size_t)NTILES * 768 * 4);
  ushort4* msgc = (ushort4*)alloc((size_t)NE * C2 / 2);

  const int* srcp = ei;
  const int* dstp = ei + NE;

  hipMemsetAsync(deg, 0, NN * sizeof(int), stream);
  k_hist<<<2048, 256, 0, stream>>>(srcp, deg);
  k_scan<<<1, 1024, 0, stream>>>(deg, cursor);
  k_scatter<<<2048, 256, 0, stream>>>(srcp, dstp, cursor, eid, ssort, dsort);

  k_wprep<<<(NC * WSZ_L + 255) / 256, 256, 0, stream>>>(convW, Wswz);
  k_wprep2<<<(NC * 2 * WNP_L + 255) / 256, 256, 0, stream>>>(convW, Wn);
  k_eaprep<<<(NTILES * 768 + 255) / 256, 256, 0, stream>>>(eid, ea, eaf);
  k_embed<<<NN / 2, 256, 0, stream>>>(x, embW, embb, h0, hbf);

  float* hc = h0;
  float* hn = h1;
  for (int L = 0; L < NC; ++L) {
    const unsigned short* Wl = Wswz + (size_t)L * WSZ_L;
    hipMemsetAsync(st_i, 0, 2 * C2 * sizeof(float), stream);
    hipMemsetAsync(st_o, 0, 2 * HD * sizeof(float), stream);
    hipMemsetAsync(agg, 0, (size_t)NN * HD * sizeof(float), stream);

    dim3 npgrid((NN + 63) / 64, 2);
    k_nodeproj2<<<npgrid, 256, 0, stream>>>(hbf, Wn, L, P1b, P3b);
    k_estat2<<<2500, 256, 0, stream>>>(ssort, dsort, eaf, Wl,
        (const uint4*)P1b, (const uint4*)P3b, msgc, st_i);
    k_apply2<<<2500, 256, 0, stream>>>(ssort, msgc, st_i, big + L * C2, bib + L * C2, agg);
    k_aggstat<<<512, 256, 0, stream>>>(agg, st_o);
    k_update<<<2048, 256, 0, stream>>>(hc, agg, st_o, bog + L * HD, bob + L * HD, hn, hbf);
    float* tmp = hc; hc = hn; hn = tmp;
  }

  hipMemsetAsync(psum, 0, (size_t)NG * HD * sizeof(float), stream);
  hipMemsetAsync(pcnt, 0, NG * sizeof(int), stream);
  k_pool<<<2048, 256, 0, stream>>>(hc, batch, psum, pcnt);
  k_head<<<NG, 128, 0, stream>>>(psum, pcnt, linW, linb, outW, outb, out);
}